// Round 7
// baseline (72.575 us; speedup 1.0000x reference)
//
#include <hip/hip_runtime.h>
#include <hip/hip_fp16.h>

typedef __attribute__((ext_vector_type(8))) _Float16 half8;
typedef __attribute__((ext_vector_type(4))) float f32x4;

union U2H2 { unsigned int u; __half2 h; };

static __device__ __forceinline__ unsigned int pack2h(float a, float b) {
    U2H2 c; c.h = __floats2half2_rn(a, b); return c.u;
}
static __device__ __forceinline__ __half2 u_as_h2(unsigned int u) {
    U2H2 c; c.u = u; return c.h;
}

// Fused prep: blocks [0,nT) transpose x -> xth [N][2][32] fp16;
// blocks [nT,nT+25) repack W -> fragment-ordered Wrh[k][ot][l][e] fp16,
//   o = ot*16 + (l&15), c = (l>>4)*8 + e.
__global__ __launch_bounds__(256) void prep_all(const float* __restrict__ x,
                                                const float* __restrict__ W,
                                                unsigned short* __restrict__ xth,
                                                unsigned short* __restrict__ Wrh,
                                                int N, int nT) {
    int bid = blockIdx.x, tid = threadIdx.x;
    if (bid >= nT) {
        int k = bid - nT;  // 0..24
#pragma unroll
        for (int it = 0; it < 8; ++it) {
            int r = tid + 256 * it;          // 0..2047
            int ot = r >> 9, lx = (r >> 3) & 63, e = r & 7;
            int o = ot * 16 + (lx & 15);
            int c = (lx >> 4) * 8 + e;
            __half h = __float2half(W[o * 800 + c * 25 + k]);
            Wrh[k * 2048 + r] = *reinterpret_cast<unsigned short*>(&h);
        }
        return;
    }
    __shared__ float t[2][32][65];
    int n0 = bid * 64;
#pragma unroll
    for (int i = 0; i < 16; ++i) {
        int e = tid + 256 * i;               // [2][32][64]
        int b = e >> 11, c = (e >> 6) & 31, nl = e & 63;
        int n = n0 + nl;
        t[b][c][nl] = (n < N) ? x[(size_t)(b * 32 + c) * N + n] : 0.f;
    }
    __syncthreads();
    int nl = tid >> 2, q = tid & 3, n = n0 + nl;
    if (n < N) {
#pragma unroll
        for (int b = 0; b < 2; ++b) {
            uint4 p;
            p.x = pack2h(t[b][q * 8 + 0][nl], t[b][q * 8 + 1][nl]);
            p.y = pack2h(t[b][q * 8 + 2][nl], t[b][q * 8 + 3][nl]);
            p.z = pack2h(t[b][q * 8 + 4][nl], t[b][q * 8 + 5][nl]);
            p.w = pack2h(t[b][q * 8 + 6][nl], t[b][q * 8 + 7][nl]);
            *reinterpret_cast<uint4*>(xth + ((size_t)n * 64 + b * 32 + q * 8)) = p;
        }
    }
}

// Fused gather + einsum + MFMA + bias. Waves fully independent: gather in
// coalesced layout (lane l -> row l>>2, slice l&3), weighted fp16 sum in-reg,
// ds_bpermute remaps to the MFMA A-fragment layout (no LDS staging, no
// barriers in the main loop). B from fragment-ordered Wrh (L1-hot).
__global__ __launch_bounds__(256, 4) void fused_main(
    const unsigned short* __restrict__ xth,  // [N][2][32] fp16
    const unsigned short* __restrict__ Wrh,  // [25][4][64][8] fp16 (fragment order)
    const float* __restrict__ bias,          // [64]
    const int* __restrict__ nidx,            // [N][25][3]
    const float* __restrict__ nw,            // [N][25][3]
    float* __restrict__ out,                 // [2][64][N] fp32
    int N)
{
    __shared__ unsigned int idxw[32 * 75];   // [nl][k*3+t]: j | half(w)<<16

    const int tid = threadIdx.x;
    const int n0 = blockIdx.x * 32;

    // ---- preload (idx, half(w)) for all 25 slices, layout [nl][75] ----
#pragma unroll
    for (int it = 0; it < 10; ++it) {
        int e = tid + 256 * it;
        if (e < 2400) {
            int n = n0 + e / 75;
            unsigned int u = 0;
            if (n < N) {
                int j = nidx[(size_t)n0 * 75 + e];
                __half hw = __float2half(nw[(size_t)n0 * 75 + e]);
                u = (unsigned int)j |
                    ((unsigned int)*reinterpret_cast<unsigned short*>(&hw) << 16);
            }
            idxw[e] = u;
        }
    }
    __syncthreads();

    const int l = tid & 63, wv = tid >> 6;
    const int row16 = l >> 2;            // gather row within this wave's 16-row tile
    const int qs = l & 3;                // 16B slice within the 64B half-row
    const int grow = 16 * wv + row16;    // 0..63 = b*32 + nl
    const int b0 = grow >> 5, nl0 = grow & 31;
    const int xoff = b0 * 32 + qs * 8;   // halfword offset in a 128B xth row
    // bpermute byte-index: MFMA lane m <- gather lane ((m&15)<<2)|(m>>4)
    const int bp = ((((l & 15) << 2) | (l >> 4)) << 2);

    const unsigned int* iprow = &idxw[nl0 * 75];

    uint4 rg[3][3];
    unsigned int ru[3][3];
    uint4 rB[2][4];

#define ISSUE_G(kk, GB)                                                 \
    do {                                                                \
        _Pragma("unroll")                                               \
        for (int t = 0; t < 3; ++t) {                                   \
            unsigned int u = iprow[(kk) * 3 + t];                       \
            ru[GB][t] = u;                                              \
            rg[GB][t] = *reinterpret_cast<const uint4*>(                \
                xth + (int)(u & 0xffffu) * 64 + xoff);                  \
        }                                                               \
    } while (0)

#define ISSUE_B(kk, BB)                                                 \
    do {                                                                \
        const unsigned short* bp_ = Wrh + (kk) * 2048 + l * 8;          \
        _Pragma("unroll")                                               \
        for (int ot = 0; ot < 4; ++ot)                                  \
            rB[BB][ot] = *reinterpret_cast<const uint4*>(bp_ + ot * 512);\
    } while (0)

    f32x4 acc[4];
#pragma unroll
    for (int ot = 0; ot < 4; ++ot) acc[ot] = (f32x4){0.f, 0.f, 0.f, 0.f};

    // prologue: B depth-2, gathers depth-3 (oldest first)
    ISSUE_B(0, 0);
    ISSUE_B(1, 1);
    ISSUE_G(0, 0);
    ISSUE_G(1, 1);
    ISSUE_G(2, 2);

#pragma unroll
    for (int k = 0; k < 25; ++k) {
        const int gb = k % 3, bb = k & 1;

        // weighted fp16 sum of the 3 gathered slices (per-lane, in-register)
        __half2 w0 = u_as_h2(__builtin_amdgcn_perm(ru[gb][0], ru[gb][0], 0x03020302u));
        __half2 w1 = u_as_h2(__builtin_amdgcn_perm(ru[gb][1], ru[gb][1], 0x03020302u));
        __half2 w2 = u_as_h2(__builtin_amdgcn_perm(ru[gb][2], ru[gb][2], 0x03020302u));
        uint4 v0 = rg[gb][0], v1 = rg[gb][1], v2 = rg[gb][2];
        uint4 p; U2H2 c;
        c.h = __hfma2(u_as_h2(v0.x), w0, __hfma2(u_as_h2(v1.x), w1, __hmul2(u_as_h2(v2.x), w2)));
        p.x = c.u;
        c.h = __hfma2(u_as_h2(v0.y), w0, __hfma2(u_as_h2(v1.y), w1, __hmul2(u_as_h2(v2.y), w2)));
        p.y = c.u;
        c.h = __hfma2(u_as_h2(v0.z), w0, __hfma2(u_as_h2(v1.z), w1, __hmul2(u_as_h2(v2.z), w2)));
        p.z = c.u;
        c.h = __hfma2(u_as_h2(v0.w), w0, __hfma2(u_as_h2(v1.w), w1, __hmul2(u_as_h2(v2.w), w2)));
        p.w = c.u;

        // refill this gather buffer 3 slices ahead (before the lgkm-waits below)
        if (k + 3 < 25) ISSUE_G(k + 3, gb);

        // wave-local lane remap to MFMA A-fragment layout
        uint4 q;
        q.x = (unsigned int)__builtin_amdgcn_ds_bpermute(bp, (int)p.x);
        q.y = (unsigned int)__builtin_amdgcn_ds_bpermute(bp, (int)p.y);
        q.z = (unsigned int)__builtin_amdgcn_ds_bpermute(bp, (int)p.z);
        q.w = (unsigned int)__builtin_amdgcn_ds_bpermute(bp, (int)p.w);
        half8 af = __builtin_bit_cast(half8, q);

        __builtin_amdgcn_s_setprio(1);
#pragma unroll
        for (int ot = 0; ot < 4; ++ot) {
            half8 bf = __builtin_bit_cast(half8, rB[bb][ot]);
            acc[ot] = __builtin_amdgcn_mfma_f32_16x16x32_f16(af, bf, acc[ot], 0, 0, 0);
        }
        __builtin_amdgcn_s_setprio(0);

        if (k + 2 < 25) ISSUE_B(k + 2, bb);  // refill the B buffer just consumed
    }

    // ---- epilogue: bias + store (D: o = ot*16 + (l&15), row = 4*(l>>4)+i) ----
    const int c16 = l & 15, g = l >> 4;
#pragma unroll
    for (int ot = 0; ot < 4; ++ot) {
        int o = ot * 16 + c16;
        float bv = bias[o];
#pragma unroll
        for (int i = 0; i < 4; ++i) {
            int mrow = 16 * wv + 4 * g + i;
            int b = mrow >> 5, nl = mrow & 31;
            int n = n0 + nl;
            if (n < N) out[(size_t)(b * 64 + o) * N + n] = acc[ot][i] + bv;
        }
    }
#undef ISSUE_G
#undef ISSUE_B
}

extern "C" void kernel_launch(void* const* d_in, const int* in_sizes, int n_in,
                              void* d_out, int out_size, void* d_ws, size_t ws_size,
                              hipStream_t stream) {
    const float* x    = (const float*)d_in[0];   // (2,32,N)
    const float* nw   = (const float*)d_in[1];   // (N,25,3)
    const float* W    = (const float*)d_in[2];   // (64,800)
    const float* bias = (const float*)d_in[3];   // (64,)
    const int*   nidx = (const int*)d_in[4];     // (N,25,3)
    float* out = (float*)d_out;

    int N = in_sizes[0] / 64;  // B*C = 64

    unsigned short* xth = (unsigned short*)d_ws;      // [N][2][32] fp16
    unsigned short* Wrh = xth + (size_t)N * 64;       // [25][4][64][8] fp16

    int nT = (N + 63) / 64;
    prep_all<<<nT + 25, 256, 0, stream>>>(x, W, xth, Wrh, N, nT);

    fused_main<<<(N + 31) / 32, 256, 0, stream>>>(xth, Wrh, bias, nidx, nw, out, N);
}